// Round 16
// baseline (23.658 us; speedup 1.0000x reference)
//
#include <hip/hip_runtime.h>

#define NH    52
#define NW    52
#define TMAX  50
#define PLANE (NH*NW)     // 2704
#define NBX   43          // 64 cells per block
#define NBA   96          // 32 batches * 3 anchors
#define NBLK  (NBA*NBX)   // 4128 blocks

__device__ __forceinline__ float softplus_fast(float x) {
    return fmaxf(x, 0.f) + __logf(1.f + __expf(-fabsf(x)));
}
__device__ __forceinline__ float rl_f(float v, int l) {
    return __int_as_float(__builtin_amdgcn_readlane(__float_as_int(v), l));
}
__device__ __forceinline__ int rl_i(int v, int l) {
    return __builtin_amdgcn_readlane(v, l);
}

// one scan step against target t (broadcast from lane t's prep registers)
#define SCAN_T(t) { \
    const float A0 = rl_f(gxl, (t)); \
    const float A1 = rl_f(gxr, (t)); \
    const float A2 = rl_f(gyl, (t)); \
    const float A3 = rl_f(gyr, (t)); \
    const float G  = rl_f(g06, (t)); \
    const int   K  = rl_i(keyv, (t)); \
    const float cw = fminf(pxr, A1) - fmaxf(pxl, A0); \
    const float ch = fminf(pyr, A3) - fmaxf(pyl, A2); \
    const float inter = fmaxf(cw, 0.f) * fmaxf(ch, 0.f); \
    ig = ig || (1.6f*inter > thr_base + G); \
    if (K == mykey) { hit = (t); ++nm; } }

__global__ __launch_bounds__(256, 8) void yolo_main(
    const float* __restrict__ inp,   // (32, 255, 52, 52)
    const float* __restrict__ tgt,   // (32, 250)
    float* __restrict__ part,        // NBLK partials (fast path)
    float* __restrict__ out,         // atomic fallback
    int use_atomic)
{
    __shared__ int   s_ex[4][64];    // [role][lane] packed (nm,ig,hit)
    __shared__ float s_red[4];

    const int tid  = threadIdx.x;
    const int lane = tid & 63;
    const int role = tid >> 6;       // 4 roles, same 64 cells
    const int cx   = blockIdx.x;
    const int ba   = blockIdx.y;     // b*3 + a
    const int b    = ba / 3;
    const int a    = ba - 3 * b;

    const float AW[9] = {1.25f, 2.0f,  4.125f, 3.75f,  7.75f,  7.375f, 14.5f,  19.5f,  46.625f};
    const float AH[9] = {1.625f,3.75f, 2.875f, 7.625f, 5.625f, 14.875f,11.25f, 24.75f, 40.75f};

    // ---------- target loads issued FIRST (ballot waits only on these) ----------
    float cls=0.f, x=0.f, y=0.f, w=0.f, h=0.f;
    if (lane < TMAX) {
        const float* tp = tgt + (size_t)b * (TMAX*5) + lane * 5;
        cls = tp[0]; x = tp[1]; y = tp[2]; w = tp[3]; h = tp[4];
    }

    // ---------- cell loads issued next (HBM latency hides under prep) ----------
    const int raw  = cx * 64 + lane;
    const bool live = raw < PLANE;
    const int idx  = live ? raw : (PLANE - 1);
    const int i = idx % NW;
    const int j = idx / NW;
    const float* base = inp + ((size_t)b * 255 + (size_t)a * 85) * PLANE + idx;
    const float lx    = base[0];
    const float ly    = base[(size_t)1*PLANE];
    const float lw    = base[(size_t)2*PLANE];
    const float lh    = base[(size_t)3*PLANE];
    const float lconf = base[(size_t)4*PLANE];

    // ---------- per-wave target prep: ALL 50 targets in lanes 0..49 ----------
    float gxl=0.f, gxr=0.f, gyl=0.f, gyr=0.f, g06=0.f;
    int   keyv=-1, clsv=0;
    float txv=0.f, tyv=0.f, twv=0.f, thv=0.f, csv=0.f;
    {
        const unsigned long long m = __ballot((lane < TMAX) ? (x != 0.f) : true);
        if (lane < TMAX) {
            const bool valid = ((~m) & ((2ull << lane) - 1ull)) == 0ull;  // cumprod 0..lane
            if (valid) {
                const float gx = x*NW, gy = y*NH, gw = w*NW, gh = h*NH;
                const float garea = gw * gh;
                // argmax over 9 anchors by IoU; cross-multiplied compare (all positive)
                float bi = fminf(gw, AW[0]) * fminf(gh, AH[0]);
                float bu = garea + AW[0]*AH[0] - bi;
                int   bn = 0;
                #pragma unroll
                for (int n = 1; n < 9; ++n) {
                    const float in_ = fminf(gw, AW[n]) * fminf(gh, AH[n]);
                    const float un_ = garea + AW[n]*AH[n] - in_;
                    if (in_ * bu > bi * un_) { bi = in_; bu = un_; bn = n; }
                }
                gxl = gx - 0.5f*gw; gxr = gx + 0.5f*gw;
                gyl = gy - 0.5f*gh; gyr = gy + 0.5f*gh;
                g06 = 0.6f * garea;
                clsv = (int)cls;
                if (bn < 3) {                       // masked anchors 0..2 selected
                    const int gi = (int)gx, gj = (int)gy;
                    if ((unsigned)gi < NW && (unsigned)gj < NH) {  // scatter mode='drop'
                        keyv = (bn << 12) | (gj << 6) | gi;
                        if (role == 0) {            // only role 0's shuffles consume these
                            txv = gx - (float)gi;
                            tyv = gy - (float)gj;
                            twv = __logf(gw / AW[bn]);
                            thv = __logf(gh / AH[bn]);
                            csv = 2.f - garea * (1.f/(float)PLANE);
                        }
                    }
                }
            }
        }
    }

    // ---------- pred box ----------
    const float sx = __builtin_amdgcn_rcpf(1.f + __expf(-lx));
    const float sy = __builtin_amdgcn_rcpf(1.f + __expf(-ly));
    const float px = sx + (float)i;
    const float py = sy + (float)j;
    const float pw = __expf(lw) * AW[a];
    const float ph = __expf(lh) * AH[a];
    const float pxl = px - 0.5f*pw, pxr = px + 0.5f*pw;
    const float pyl = py - 0.5f*ph, pyr = py + 0.5f*ph;
    const float thr_base = 0.6f * (pw * ph);   // 0.6*parea
    const int   mykey = (a << 12) | (j << 6) | i;

    // ---------- quarter-range scan: role r -> {0-12, 13-25, 26-37, 38-49} ----------
    bool ig = false;
    int  hit = -1;                              // last-wins within range
    int  nm  = 0;                               // match count within range
    if (role == 0) {
        #pragma unroll
        for (int t = 0;  t < 13; ++t) SCAN_T(t)
    } else if (role == 1) {
        #pragma unroll
        for (int t = 13; t < 26; ++t) SCAN_T(t)
    } else if (role == 2) {
        #pragma unroll
        for (int t = 26; t < 38; ++t) SCAN_T(t)
    } else {
        #pragma unroll
        for (int t = 38; t < 50; ++t) SCAN_T(t)
    }

    // ---------- 4-way exchange: every wave learns the combined result ----------
    // pack: [5:0] hit+1, [6] ig, [12:7] nm
    s_ex[role][lane] = (nm << 7) | (ig ? 64 : 0) | (hit + 1);
    __syncthreads();
    const int w0 = s_ex[0][lane];
    const int w1 = s_ex[1][lane];
    const int w2 = s_ex[2][lane];
    const int w3 = s_ex[3][lane];
    const int h0 = (w0 & 63) - 1, h1 = (w1 & 63) - 1;
    const int h2 = (w2 & 63) - 1, h3 = (w3 & 63) - 1;
    const bool ignored = ((w0 | w1 | w2 | w3) & 64) != 0;
    const int nmT = (w0 >> 7) + (w1 >> 7) + (w2 >> 7) + (w3 >> 7);
    const int hitC = (h3 >= 0) ? h3 : (h2 >= 0) ? h2 : (h1 >= 0) ? h1 : h0;  // last-wins

    float acc = 0.f;
    // conf loss: role 0 only (counted once per cell)
    if (role == 0) {
        const float tconf = (hitC >= 0) ? 1.f : (ignored ? -1.f : 0.f);
        if (tconf != -1.f)
            acc += softplus_fast(lconf) - tconf * lconf;
    }

    unsigned long long cmask0 = 0ull, cmask1 = 0ull;
    const unsigned long long hb = __ballot(live && (hitC >= 0));
    if (hb) {
        // coord losses: role 0 only; hit target data via wave-local shuffles
        if (role == 0) {
            const int hsrc = (hitC >= 0) ? hitC : 0;
            const float tx_ = __shfl(txv, hsrc, 64);
            const float ty_ = __shfl(tyv, hsrc, 64);
            const float tw_ = __shfl(twv, hsrc, 64);
            const float th_ = __shfl(thv, hsrc, 64);
            const float cs_ = __shfl(csv, hsrc, 64);
            if (hitC >= 0) {
                acc += cs_ * (softplus_fast(lx) - tx_ * lx);
                acc += cs_ * (softplus_fast(ly) - ty_ * ly);
                const float dw = lw - tw_;
                const float dh = lh - th_;
                acc += 0.5f * cs_ * (dw*dw + dh*dh);
            }
        }
        // class bitmask: common case (no duplicate targets on any cell of this wave)
        // is a single class bit from hitC; rare duplicate case does the full rescan.
        const unsigned long long dupb = __ballot(live && (hitC >= 0) && (nmT > 1));
        if (dupb == 0ull) {
            const int C_ = __shfl(clsv, (hitC >= 0) ? hitC : 0, 64);
            if (hitC >= 0) {
                if (C_ < 64) cmask0 = 1ull << C_;
                else         cmask1 = 1ull << (C_ - 64);
            }
        } else {
            #pragma unroll
            for (int t = 0; t < TMAX; ++t) {
                const int K = rl_i(keyv, t);
                const int C = rl_i(clsv, t);
                if (hitC >= 0 && K == mykey) {
                    if (C < 64) cmask0 |= (1ull << C);
                    else        cmask1 |= (1ull << (C - 64));
                }
            }
        }
    }

    if (!live) acc = 0.f;

    // ---------- wave-cooperative class loss on 4 waves, disjoint class quarters ----------
    // role r: classes 16r..16r+15 (lanes 16r..16r+15) + 64+4r..64+4r+3 (lanes 4r..4r+3)
    const bool sel0 = (lane >> 4) == role;
    const bool sel1 = (lane < 16) && ((lane >> 2) == role);
    unsigned long long hmask = hb;
    while (hmask) {
        const int src = __ffsll(hmask) - 1;
        hmask &= (hmask - 1);
        const int  sidx  = __shfl(idx, src, 64);
        const int  signd = __shfl((int)ignored, src, 64);
        const unsigned m0lo = (unsigned)__shfl((int)(unsigned)(cmask0      ), src, 64);
        const unsigned m0hi = (unsigned)__shfl((int)(unsigned)(cmask0 >> 32), src, 64);
        const unsigned m1lo = (unsigned)__shfl((int)(unsigned)(cmask1      ), src, 64);

        const float* cbase = inp + ((size_t)b * 255 + (size_t)a * 85 + 5) * PLANE + sidx;
        const bool one0 = (lane < 32) ? ((m0lo >> lane) & 1u) : ((m0hi >> (lane - 32)) & 1u);
        const bool one1 = (lane < 16) && ((m1lo >> lane) & 1u);

        if (signd) {
            if (sel0) {
                const float l0 = cbase[(size_t)lane * PLANE];
                acc += softplus_fast(l0) - (one0 ? l0 : 0.f);
            }
            if (sel1) {
                const float l1 = cbase[(size_t)(64 + lane) * PLANE];
                acc += softplus_fast(l1) - (one1 ? l1 : 0.f);
            }
        } else {
            if (one0 && sel0) {
                const float l0 = cbase[(size_t)lane * PLANE];
                acc += softplus_fast(l0) - l0;
            }
            if (one1 && sel1) {
                const float l1 = cbase[(size_t)(64 + lane) * PLANE];
                acc += softplus_fast(l1) - l1;
            }
        }
    }

    // ---------- wave reduce -> LDS -> block partial ----------
    for (int off = 32; off > 0; off >>= 1)
        acc += __shfl_down(acc, off, 64);
    if (lane == 0) s_red[role] = acc;
    __syncthreads();
    if (tid == 0) {
        const float s = s_red[0] + s_red[1] + s_red[2] + s_red[3];
        if (use_atomic) atomicAdd(out, s);
        else part[ba * NBX + cx] = s;
    }
}

__global__ __launch_bounds__(1024) void yolo_reduce(
    const float* __restrict__ part, float* __restrict__ out)
{
    __shared__ float s[16];
    const int tid = threadIdx.x;
    float a = 0.f;
    for (int k = tid; k < NBLK / 4; k += 1024) {   // 1032 float4 loads
        const float4 v = ((const float4*)part)[k];
        a += (v.x + v.y) + (v.z + v.w);
    }
    for (int off = 32; off > 0; off >>= 1)
        a += __shfl_down(a, off, 64);
    if ((tid & 63) == 0) s[tid >> 6] = a;
    __syncthreads();
    if (tid == 0) {
        float t = 0.f;
        #pragma unroll
        for (int k = 0; k < 16; ++k) t += s[k];
        out[0] = t;
    }
}

extern "C" void kernel_launch(void* const* d_in, const int* in_sizes, int n_in,
                              void* d_out, int out_size, void* d_ws, size_t ws_size,
                              hipStream_t stream) {
    const float* inp = (const float*)d_in[0];   // (32, 255, 52, 52) f32
    const float* tgt = (const float*)d_in[1];   // (32, 250) f32
    float* out = (float*)d_out;                 // 1 f32

    dim3 grid(NBX, NBA);                         // 43 x 96

    if (ws_size >= (size_t)NBLK * sizeof(float)) {
        float* part = (float*)d_ws;
        yolo_main<<<grid, dim3(256), 0, stream>>>(inp, tgt, part, out, 0);
        yolo_reduce<<<dim3(1), dim3(1024), 0, stream>>>(part, out);
    } else {
        (void)hipMemsetAsync(out, 0, sizeof(float), stream);
        yolo_main<<<grid, dim3(256), 0, stream>>>(inp, tgt, nullptr, out, 1);
    }
}

// Round 17
// 21.773 us; speedup vs baseline: 1.0866x; 1.0866x over previous
//
#include <hip/hip_runtime.h>

#define NH    52
#define NW    52
#define TMAX  50
#define PLANE (NH*NW)     // 2704
#define NBX   22          // 128 cells per block
#define NBA   96          // 32 batches * 3 anchors
#define NBLK  (NBA*NBX)   // 2112 blocks

__device__ __forceinline__ float softplus_fast(float x) {
    return fmaxf(x, 0.f) + __logf(1.f + __expf(-fabsf(x)));
}
__device__ __forceinline__ float rl_f(float v, int l) {
    return __int_as_float(__builtin_amdgcn_readlane(__float_as_int(v), l));
}
__device__ __forceinline__ int rl_i(int v, int l) {
    return __builtin_amdgcn_readlane(v, l);
}

// one scan step against target t (broadcast from lane t's prep registers)
#define SCAN_T(t) { \
    const float A0 = rl_f(gxl, (t)); \
    const float A1 = rl_f(gxr, (t)); \
    const float A2 = rl_f(gyl, (t)); \
    const float A3 = rl_f(gyr, (t)); \
    const float G  = rl_f(g06, (t)); \
    const int   K  = rl_i(keyv, (t)); \
    const float cw = fminf(pxr, A1) - fmaxf(pxl, A0); \
    const float ch = fminf(pyr, A3) - fmaxf(pyl, A2); \
    const float inter = fmaxf(cw, 0.f) * fmaxf(ch, 0.f); \
    ig = ig || (1.6f*inter > thr_base + G); \
    if (K == mykey) { hit = (t); ++nm; } }

__global__ __launch_bounds__(256, 8) void yolo_main(
    const float* __restrict__ inp,   // (32, 255, 52, 52)
    const float* __restrict__ tgt,   // (32, 250)
    float* __restrict__ part,        // NBLK partials (fast path)
    float* __restrict__ out,         // atomic fallback
    int use_atomic)
{
    __shared__ int   s_ex[2][2][64];   // [group][role][lane] packed (nm,ig,hit)
    __shared__ float s_red[4];

    const int tid  = threadIdx.x;
    const int lane = tid & 63;
    const int wv   = tid >> 6;
    const int grp  = wv >> 1;        // cell group 0/1 within block
    const int role = wv & 1;         // 0 = lo targets (primary), 1 = hi targets
    const bool hiR = role != 0;
    const int cx   = blockIdx.x;
    const int ba   = blockIdx.y;     // b*3 + a
    const int b    = ba / 3;
    const int a    = ba - 3 * b;

    const float AW[9] = {1.25f, 2.0f,  4.125f, 3.75f,  7.75f,  7.375f, 14.5f,  19.5f,  46.625f};
    const float AH[9] = {1.625f,3.75f, 2.875f, 7.625f, 5.625f, 14.875f,11.25f, 24.75f, 40.75f};

    // ---------- target loads issued FIRST (ballot waits only on these) ----------
    float cls=0.f, x=0.f, y=0.f, w=0.f, h=0.f;
    if (lane < TMAX) {
        const float* tp = tgt + (size_t)b * (TMAX*5) + lane * 5;
        cls = tp[0]; x = tp[1]; y = tp[2]; w = tp[3]; h = tp[4];
    }

    // ---------- cell loads issued next (HBM latency hides under prep) ----------
    const int raw  = cx * 128 + grp * 64 + lane;
    const bool live = raw < PLANE;
    const int idx  = live ? raw : (PLANE - 1);
    const int i = idx % NW;
    const int j = idx / NW;
    const float* base = inp + ((size_t)b * 255 + (size_t)a * 85) * PLANE + idx;
    const float lx    = base[0];
    const float ly    = base[(size_t)1*PLANE];
    const float lw    = base[(size_t)2*PLANE];
    const float lh    = base[(size_t)3*PLANE];
    const float lconf = base[(size_t)4*PLANE];

    // ---------- per-wave target prep: ALL 50 targets in lanes 0..49 ----------
    float gxl=0.f, gxr=0.f, gyl=0.f, gyr=0.f, g06=0.f;
    int   keyv=-1, clsv=0;
    float txv=0.f, tyv=0.f, twv=0.f, thv=0.f, csv=0.f;
    {
        const unsigned long long m = __ballot((lane < TMAX) ? (x != 0.f) : true);
        if (lane < TMAX) {
            const bool valid = ((~m) & ((2ull << lane) - 1ull)) == 0ull;  // cumprod 0..lane
            if (valid) {
                const float gx = x*NW, gy = y*NH, gw = w*NW, gh = h*NH;
                const float garea = gw * gh;
                // argmax over 9 anchors by IoU; cross-multiplied compare (all positive)
                float bi = fminf(gw, AW[0]) * fminf(gh, AH[0]);
                float bu = garea + AW[0]*AH[0] - bi;
                int   bn = 0;
                #pragma unroll
                for (int n = 1; n < 9; ++n) {
                    const float in_ = fminf(gw, AW[n]) * fminf(gh, AH[n]);
                    const float un_ = garea + AW[n]*AH[n] - in_;
                    if (in_ * bu > bi * un_) { bi = in_; bu = un_; bn = n; }
                }
                gxl = gx - 0.5f*gw; gxr = gx + 0.5f*gw;
                gyl = gy - 0.5f*gh; gyr = gy + 0.5f*gh;
                g06 = 0.6f * garea;
                clsv = (int)cls;
                if (bn < 3) {                       // masked anchors 0..2 selected
                    const int gi = (int)gx, gj = (int)gy;
                    if ((unsigned)gi < NW && (unsigned)gj < NH) {  // scatter mode='drop'
                        keyv = (bn << 12) | (gj << 6) | gi;
                        txv = gx - (float)gi;
                        tyv = gy - (float)gj;
                        twv = __logf(gw / AW[bn]);
                        thv = __logf(gh / AH[bn]);
                        csv = 2.f - garea * (1.f/(float)PLANE);
                    }
                }
            }
        }
    }

    // ---------- pred box ----------
    const float sx = __builtin_amdgcn_rcpf(1.f + __expf(-lx));
    const float sy = __builtin_amdgcn_rcpf(1.f + __expf(-ly));
    const float px = sx + (float)i;
    const float py = sy + (float)j;
    const float pw = __expf(lw) * AW[a];
    const float ph = __expf(lh) * AH[a];
    const float pxl = px - 0.5f*pw, pxr = px + 0.5f*pw;
    const float pyl = py - 0.5f*ph, pyr = py + 0.5f*ph;
    const float thr_base = 0.6f * (pw * ph);   // 0.6*parea
    const int   mykey = (a << 12) | (j << 6) | i;

    // ---------- half-range scan: role 0 -> t=0..24, role 1 -> t=25..49 ----------
    bool ig = false;
    int  hit = -1;                              // last-wins within range
    int  nm  = 0;                               // match count within range
    if (hiR) {
        #pragma unroll
        for (int t = 25; t < 50; ++t) SCAN_T(t)
    } else {
        #pragma unroll
        for (int t = 0; t < 25; ++t) SCAN_T(t)
    }

    // ---------- bidirectional exchange: both waves learn the combined result ----------
    // pack: [5:0] hit+1, [6] ig, [11:7] nm
    s_ex[grp][role][lane] = (nm << 7) | (ig ? 64 : 0) | (hit + 1);
    __syncthreads();
    const int other    = s_ex[grp][role ^ 1][lane];
    const int hit_oth  = (other & 63) - 1;
    const bool ignored = ig || ((other & 64) != 0);
    const int nmT      = nm + (other >> 7);     // total matches at this cell
    const int hit_lo   = hiR ? hit_oth : hit;
    const int hit_hi   = hiR ? hit : hit_oth;
    const int hitC     = (hit_hi >= 0) ? hit_hi : hit_lo;   // last-wins overall

    float acc = 0.f;
    // conf loss: primary only (counted once per cell)
    if (!hiR) {
        const float tconf = (hitC >= 0) ? 1.f : (ignored ? -1.f : 0.f);
        if (tconf != -1.f)
            acc += softplus_fast(lconf) - tconf * lconf;
    }

    unsigned long long cmask0 = 0ull, cmask1 = 0ull;
    const unsigned long long hb = __ballot(live && (hitC >= 0));
    if (hb) {
        // coord losses: primary only; hit target data via wave-local shuffles
        if (!hiR) {
            const int hsrc = (hitC >= 0) ? hitC : 0;
            const float tx_ = __shfl(txv, hsrc, 64);
            const float ty_ = __shfl(tyv, hsrc, 64);
            const float tw_ = __shfl(twv, hsrc, 64);
            const float th_ = __shfl(thv, hsrc, 64);
            const float cs_ = __shfl(csv, hsrc, 64);
            if (hitC >= 0) {
                acc += cs_ * (softplus_fast(lx) - tx_ * lx);
                acc += cs_ * (softplus_fast(ly) - ty_ * ly);
                const float dw = lw - tw_;
                const float dh = lh - th_;
                acc += 0.5f * cs_ * (dw*dw + dh*dh);
            }
        }
        // class bitmask: common case (no duplicate targets on any cell of this wave)
        // is a single class bit from hitC; rare duplicate case does the full rescan.
        const unsigned long long dupb = __ballot(live && (hitC >= 0) && (nmT > 1));
        if (dupb == 0ull) {
            const int C_ = __shfl(clsv, (hitC >= 0) ? hitC : 0, 64);
            if (hitC >= 0) {
                if (C_ < 64) cmask0 = 1ull << C_;
                else         cmask1 = 1ull << (C_ - 64);
            }
        } else {
            #pragma unroll
            for (int t = 0; t < TMAX; ++t) {
                const int K = rl_i(keyv, t);
                const int C = rl_i(clsv, t);
                if (hitC >= 0 && K == mykey) {
                    if (C < 64) cmask0 |= (1ull << C);
                    else        cmask1 |= (1ull << (C - 64));
                }
            }
        }
    }

    if (!live) acc = 0.f;

    // ---------- wave-cooperative class loss on BOTH waves, disjoint class halves ----------
    // primary: classes 0..31 (lanes 0..31) + 64..71 (lanes 0..7)
    // hi:      classes 32..63 (lanes 32..63) + 72..79 (lanes 8..15)
    const bool sel0 = hiR ? (lane >= 32) : (lane < 32);
    const bool sel1 = hiR ? (lane >= 8 && lane < 16) : (lane < 8);
    unsigned long long hmask = hb;
    while (hmask) {
        const int src = __ffsll(hmask) - 1;
        hmask &= (hmask - 1);
        const int  sidx  = __shfl(idx, src, 64);
        const int  signd = __shfl((int)ignored, src, 64);
        const unsigned m0lo = (unsigned)__shfl((int)(unsigned)(cmask0      ), src, 64);
        const unsigned m0hi = (unsigned)__shfl((int)(unsigned)(cmask0 >> 32), src, 64);
        const unsigned m1lo = (unsigned)__shfl((int)(unsigned)(cmask1      ), src, 64);

        const float* cbase = inp + ((size_t)b * 255 + (size_t)a * 85 + 5) * PLANE + sidx;
        const bool one0 = (lane < 32) ? ((m0lo >> lane) & 1u) : ((m0hi >> (lane - 32)) & 1u);
        const bool one1 = (lane < 16) && ((m1lo >> lane) & 1u);

        if (signd) {
            if (sel0) {
                const float l0 = cbase[(size_t)lane * PLANE];
                acc += softplus_fast(l0) - (one0 ? l0 : 0.f);
            }
            if (sel1) {
                const float l1 = cbase[(size_t)(64 + lane) * PLANE];
                acc += softplus_fast(l1) - (one1 ? l1 : 0.f);
            }
        } else {
            if (one0 && sel0) {
                const float l0 = cbase[(size_t)lane * PLANE];
                acc += softplus_fast(l0) - l0;
            }
            if (one1 && sel1) {
                const float l1 = cbase[(size_t)(64 + lane) * PLANE];
                acc += softplus_fast(l1) - l1;
            }
        }
    }

    // ---------- wave reduce -> LDS -> block partial ----------
    for (int off = 32; off > 0; off >>= 1)
        acc += __shfl_down(acc, off, 64);
    if (lane == 0) s_red[wv] = acc;
    __syncthreads();
    if (tid == 0) {
        const float s = s_red[0] + s_red[1] + s_red[2] + s_red[3];
        if (use_atomic) atomicAdd(out, s);
        else part[ba * NBX + cx] = s;
    }
}

__global__ __launch_bounds__(1024) void yolo_reduce(
    const float* __restrict__ part, float* __restrict__ out)
{
    __shared__ float s[16];
    const int tid = threadIdx.x;
    float a = 0.f;
    if (tid < NBLK / 4) {                        // 528 float4 loads, one round
        const float4 v = ((const float4*)part)[tid];
        a = (v.x + v.y) + (v.z + v.w);
    }
    for (int off = 32; off > 0; off >>= 1)
        a += __shfl_down(a, off, 64);
    if ((tid & 63) == 0) s[tid >> 6] = a;
    __syncthreads();
    if (tid == 0) {
        float t = 0.f;
        #pragma unroll
        for (int k = 0; k < 16; ++k) t += s[k];
        out[0] = t;
    }
}

extern "C" void kernel_launch(void* const* d_in, const int* in_sizes, int n_in,
                              void* d_out, int out_size, void* d_ws, size_t ws_size,
                              hipStream_t stream) {
    const float* inp = (const float*)d_in[0];   // (32, 255, 52, 52) f32
    const float* tgt = (const float*)d_in[1];   // (32, 250) f32
    float* out = (float*)d_out;                 // 1 f32

    dim3 grid(NBX, NBA);                         // 22 x 96

    if (ws_size >= (size_t)NBLK * sizeof(float)) {
        float* part = (float*)d_ws;
        yolo_main<<<grid, dim3(256), 0, stream>>>(inp, tgt, part, out, 0);
        yolo_reduce<<<dim3(1), dim3(1024), 0, stream>>>(part, out);
    } else {
        (void)hipMemsetAsync(out, 0, sizeof(float), stream);
        yolo_main<<<grid, dim3(256), 0, stream>>>(inp, tgt, nullptr, out, 1);
    }
}